// Round 13
// baseline (109.046 us; speedup 1.0000x reference)
//
#include <hip/hip_runtime.h>

// CoLL fused, 2 dispatches, NO atomics:
//  A) reduce_k : per-block min/max partials -> d_ws (2048 float2)
//  B) coll_k   : 2-ROW REGISTER BLOCKING — each thread computes pixels
//     (h0, h0+1): 4x3 load patch serves both 3x3 stencils.
//     co[8][8] in ONE VGPR/lane; gather via ds_bpermute.
//     y(p,c) = sum_{3x3} w[dq] * x(q,c) * co[bin(p,c), bin(q,c)]
// N=8, H=128, W=128, C=64, NUM_BINS=8. One image = 128*128*16 = 262144 float4.

static constexpr int IMG4 = 128 * 128 * 16;
static constexpr int TOT4 = 8 * IMG4;            // 2097152 float4
static constexpr int RBLK = 2048;                // reduce blocks
static constexpr int RSTRIDE = RBLK * 256;       // 524288; TOT4/RSTRIDE = 4
static constexpr int CBLK = 512, NTHR = 256;     // coll: 131072 thr x 2 pixels

__device__ __forceinline__ int qbin(float v, float xmin, float scale) {
    float t = (v - xmin) * scale;   // >= 0 exactly (v >= xmin in f32)
    t = fminf(t, 7.0f);
    return (int)t;                  // trunc == floor for t >= 0
}

__global__ __launch_bounds__(256) void reduce_k(const float4* __restrict__ x4,
                                                float2* __restrict__ part) {
    const int i = blockIdx.x * 256 + threadIdx.x;
    float4 a = x4[i];
    float4 b = x4[i + RSTRIDE];
    float4 c = x4[i + 2 * RSTRIDE];
    float4 d = x4[i + 3 * RSTRIDE];
    float lmin = fminf(fminf(fminf(a.x, a.y), fminf(a.z, a.w)),
                       fminf(fminf(b.x, b.y), fminf(b.z, b.w)));
    float lmax = fmaxf(fmaxf(fmaxf(a.x, a.y), fmaxf(a.z, a.w)),
                       fmaxf(fmaxf(b.x, b.y), fmaxf(b.z, b.w)));
    lmin = fminf(lmin, fminf(fminf(fminf(c.x, c.y), fminf(c.z, c.w)),
                             fminf(fminf(d.x, d.y), fminf(d.z, d.w))));
    lmax = fmaxf(lmax, fmaxf(fmaxf(fmaxf(c.x, c.y), fmaxf(c.z, c.w)),
                             fmaxf(fmaxf(d.x, d.y), fmaxf(d.z, d.w))));
#pragma unroll
    for (int off = 32; off; off >>= 1) {
        lmin = fminf(lmin, __shfl_xor(lmin, off, 64));
        lmax = fmaxf(lmax, __shfl_xor(lmax, off, 64));
    }
    __shared__ float smin[4], smax[4];
    const int wid = threadIdx.x >> 6, lane = threadIdx.x & 63;
    if (lane == 0) { smin[wid] = lmin; smax[wid] = lmax; }
    __syncthreads();
    if (threadIdx.x == 0) {
        part[blockIdx.x] = make_float2(
            fminf(fminf(smin[0], smin[1]), fminf(smin[2], smin[3])),
            fmaxf(fmaxf(smax[0], smax[1]), fmaxf(smax[2], smax[3])));
    }
}

__global__ __launch_bounds__(256) void coll_k(const float4* __restrict__ x4,
                                              const float* __restrict__ co,
                                              const float* __restrict__ wsp,
                                              float4* __restrict__ y4,
                                              const float2* __restrict__ part) {
    __shared__ float sred[8];

    // prologue: every block redundantly reduces the 2048 partials (16 KB, L2-hot)
    float gmin = 3.4028235e38f, gmax = -3.4028235e38f;
#pragma unroll
    for (int j = 0; j < 8; ++j) {
        float2 p = part[threadIdx.x * 8 + j];
        gmin = fminf(gmin, p.x);
        gmax = fmaxf(gmax, p.y);
    }
#pragma unroll
    for (int off = 32; off; off >>= 1) {
        gmin = fminf(gmin, __shfl_xor(gmin, off, 64));
        gmax = fmaxf(gmax, __shfl_xor(gmax, off, 64));
    }
    const int wid = threadIdx.x >> 6, lane = threadIdx.x & 63;
    if (lane == 0) { sred[wid] = gmin; sred[4 + wid] = gmax; }
    __syncthreads();
    const float xmin = fminf(fminf(sred[0], sred[1]), fminf(sred[2], sred[3]));
    const float xmax = fmaxf(fmaxf(sred[4], sred[5]), fmaxf(sred[6], sred[7]));
    const float scale = 8.0f / ((xmax - xmin) + 1e-8f);

    // co table: one VGPR per lane holds co[lane] (64 entries == one wave)
    const int co_i = __float_as_int(co[lane]);

    // thread -> (c4, w, hb): pixels (h0, h0+1), h0 = 2*hb
    const int i = blockIdx.x * 256 + threadIdx.x;
    const int c4 = i & 15;
    const int w  = (i >> 4) & 127;
    const int hb = i >> 11;               // 0..63
    const int h0 = hb << 1;

    const bool vm = (w > 0), vp = (w < 127);
    const bool vt = (h0 > 0), vb = (hb < 63);   // top row rm / bottom row rp

    const int o4 = h0 * 2048 + w * 16 + c4;     // (r0, w) = P0 center
    // 12-point patch offsets (clamped to o4 when invalid), hoisted out of k-loop
    const int o0 = (vt && vm) ? o4 - 2064 : o4, o1 = vt ? o4 - 2048 : o4;
    const int o2 = (vt && vp) ? o4 - 2032 : o4, o3 = vm ? o4 - 16 : o4;
    const int o5 = vp ? o4 + 16 : o4,           o6 = vm ? o4 + 2032 : o4;
    const int o7 = o4 + 2048;                   // (r1, w) = P1 center
    const int o8 = vp ? o4 + 2064 : o4;
    const int o9 = (vb && vm) ? o4 + 4080 : o4, o10 = vb ? o4 + 4096 : o4;
    const int o11 = (vb && vp) ? o4 + 4112 : o4;

    // per-pixel tap weights (uniform s-loads, zeroed per-lane when invalid)
    const float s0 = wsp[0], s1 = wsp[1], s2 = wsp[2], s3 = wsp[3], s4 = wsp[4],
                s5 = wsp[5], s6 = wsp[6], s7 = wsp[7], s8 = wsp[8];
    // P0: rows rm(w0..2) r0(w3..5) r1(w6..8)
    const float z00 = (vt && vm) ? s0 : 0.f, z01 = vt ? s1 : 0.f,
                z02 = (vt && vp) ? s2 : 0.f;
    const float z03 = vm ? s3 : 0.f, z04 = s4, z05 = vp ? s5 : 0.f;
    const float z06 = vm ? s6 : 0.f, z07 = s7, z08 = vp ? s8 : 0.f;
    // P1: rows r0(w0..2) r1(w3..5) rp(w6..8)
    const float z10 = vm ? s0 : 0.f, z11 = s1, z12 = vp ? s2 : 0.f;
    const float z13 = vm ? s3 : 0.f, z14 = s4, z15 = vp ? s5 : 0.f;
    const float z16 = (vb && vm) ? s6 : 0.f, z17 = vb ? s7 : 0.f,
                z18 = (vb && vp) ? s8 : 0.f;

#define BP(A) __int_as_float(__builtin_amdgcn_ds_bpermute((A), co_i))

#pragma unroll 1
    for (int k = 0; k < 8; ++k) {
        const int kb = k * IMG4;
        // ---- 12 independent loads ----
        const float4 q0 = x4[kb + o0], q1 = x4[kb + o1], q2 = x4[kb + o2];
        const float4 q3 = x4[kb + o3], q4 = x4[kb + o4], q5 = x4[kb + o5];
        const float4 q6 = x4[kb + o6], q7 = x4[kb + o7], q8 = x4[kb + o8];
        const float4 q9 = x4[kb + o9], q10 = x4[kb + o10], q11 = x4[kb + o11];

        // center-row byte offsets (bp * 8 entries * 4 B = bp<<5)
        const int i0x = qbin(q4.x, xmin, scale) << 5;
        const int i0y = qbin(q4.y, xmin, scale) << 5;
        const int i0z = qbin(q4.z, xmin, scale) << 5;
        const int i0w = qbin(q4.w, xmin, scale) << 5;
        const int i1x = qbin(q7.x, xmin, scale) << 5;
        const int i1y = qbin(q7.y, xmin, scale) << 5;
        const int i1z = qbin(q7.z, xmin, scale) << 5;
        const int i1w = qbin(q7.w, xmin, scale) << 5;

        float a0x = 0.f, a0y = 0.f, a0z = 0.f, a0w = 0.f;
        float a1x = 0.f, a1y = 0.f, a1z = 0.f, a1w = 0.f;
        int bx, by, bz, bw;

#define QB4(Q) { bx = qbin(Q.x, xmin, scale) << 2; by = qbin(Q.y, xmin, scale) << 2; \
                 bz = qbin(Q.z, xmin, scale) << 2; bw = qbin(Q.w, xmin, scale) << 2; }
#define ACC0(Q, WZ) { a0x = fmaf((WZ) * Q.x, BP(i0x + bx), a0x); \
                      a0y = fmaf((WZ) * Q.y, BP(i0y + by), a0y); \
                      a0z = fmaf((WZ) * Q.z, BP(i0z + bz), a0z); \
                      a0w = fmaf((WZ) * Q.w, BP(i0w + bw), a0w); }
#define ACC1(Q, WZ) { a1x = fmaf((WZ) * Q.x, BP(i1x + bx), a1x); \
                      a1y = fmaf((WZ) * Q.y, BP(i1y + by), a1y); \
                      a1z = fmaf((WZ) * Q.z, BP(i1z + bz), a1z); \
                      a1w = fmaf((WZ) * Q.w, BP(i1w + bw), a1w); }

        QB4(q0)  ACC0(q0, z00)
        QB4(q1)  ACC0(q1, z01)
        QB4(q2)  ACC0(q2, z02)
        QB4(q3)  ACC0(q3, z03)  ACC1(q3, z10)
        QB4(q4)  ACC0(q4, z04)  ACC1(q4, z11)
        QB4(q5)  ACC0(q5, z05)  ACC1(q5, z12)
        QB4(q6)  ACC0(q6, z06)  ACC1(q6, z13)
        QB4(q7)  ACC0(q7, z07)  ACC1(q7, z14)
        QB4(q8)  ACC0(q8, z08)  ACC1(q8, z15)
        QB4(q9)  ACC1(q9, z16)
        QB4(q10) ACC1(q10, z17)
        QB4(q11) ACC1(q11, z18)
#undef QB4
#undef ACC0
#undef ACC1

        y4[kb + o4] = make_float4(a0x, a0y, a0z, a0w);
        y4[kb + o7] = make_float4(a1x, a1y, a1z, a1w);
    }
#undef BP
}

extern "C" void kernel_launch(void* const* d_in, const int* in_sizes, int n_in,
                              void* d_out, int out_size, void* d_ws, size_t ws_size,
                              hipStream_t stream) {
    const float4* x4 = (const float4*)d_in[0];
    const float*  co = (const float*)d_in[1];
    const float*  wsp = (const float*)d_in[2];
    float4* y4 = (float4*)d_out;
    float2* part = (float2*)d_ws;    // 2048 float2 = 16 KB scratch

    hipLaunchKernelGGL(reduce_k, dim3(RBLK), dim3(NTHR), 0, stream, x4, part);
    hipLaunchKernelGGL(coll_k, dim3(CBLK), dim3(NTHR), 0, stream,
                       x4, co, wsp, y4, part);
}